// Round 2
// baseline (332.390 us; speedup 1.0000x reference)
//
#include <hip/hip_runtime.h>
#include <hip/hip_bf16.h>

#define NL 8
#define HD 4096
#define RD 64
#define MD 4096
#define NGC 512  // NL*RD

typedef __bf16 bf16x8 __attribute__((ext_vector_type(8)));
typedef float f32x4 __attribute__((ext_vector_type(4)));
typedef unsigned short ushort8 __attribute__((ext_vector_type(8)));
typedef float float4v __attribute__((ext_vector_type(4)));

__device__ __forceinline__ unsigned short f2bf(float f) {
    union { __hip_bfloat16 b; unsigned short u; } c;
    c.b = __float2bfloat16(f);
    return c.u;
}

__device__ __forceinline__ void gload_lds16(const void* g, void* l) {
    auto gp = (const __attribute__((address_space(1))) unsigned int*)(g);
    auto lp = (__attribute__((address_space(3))) unsigned int*)(l);
    __builtin_amdgcn_global_load_lds(gp, lp, 16, 0, 0);
}

// lora_A [NL][HD][RD] f32 -> At [NL*RD][HD] bf16  (At[n*64+r][h] = A[n][h][r])
__global__ __launch_bounds__(256) void k_prep_A(const float* __restrict__ A,
                                                unsigned short* __restrict__ At) {
    __shared__ unsigned short T[64][65];
    int t = threadIdx.x;
    int n = blockIdx.x >> 6;
    int h0 = (blockIdx.x & 63) << 6;
    const float* src = A + (size_t)n * HD * RD;
#pragma unroll
    for (int rep = 0; rep < 16; ++rep) {
        int flat = rep * 256 + t;
        int hh = flat >> 6, rr = flat & 63;
        T[hh][rr] = f2bf(src[(size_t)(h0 + hh) * RD + rr]);
    }
    __syncthreads();
#pragma unroll
    for (int rep = 0; rep < 16; ++rep) {
        int flat = rep * 256 + t;
        int rr = flat >> 6, hh = flat & 63;
        At[(size_t)(n * RD + rr) * HD + h0 + hh] = T[hh][rr];
    }
}

// lora_B [NL][RD][HD] f32 -> Bt [NL][HD][RD] bf16  (Bt[n][h][r] = B[n][r][h])
__global__ __launch_bounds__(256) void k_prep_B(const float* __restrict__ B,
                                                unsigned short* __restrict__ Bt) {
    __shared__ unsigned short T[64][65];
    int t = threadIdx.x;
    int n = blockIdx.x >> 6;
    int h0 = (blockIdx.x & 63) << 6;
    const float* src = B + (size_t)n * RD * HD;
#pragma unroll
    for (int rep = 0; rep < 16; ++rep) {
        int flat = rep * 256 + t;
        int rr = flat >> 6, hh = flat & 63;
        T[rr][hh] = f2bf(src[(size_t)rr * HD + h0 + hh]);
    }
    __syncthreads();
    unsigned short* dst = Bt + (size_t)n * HD * RD;
#pragma unroll
    for (int rep = 0; rep < 16; ++rep) {
        int flat = rep * 256 + t;
        int hh = flat >> 6, rr = flat & 63;
        dst[(size_t)(h0 + hh) * RD + rr] = T[rr][hh];
    }
}

// G[n] = B_n @ B_n^T  (fp32, atomic K-chunked)
__global__ __launch_bounds__(256) void k_gram(const float* __restrict__ B,
                                              float* __restrict__ G) {
    __shared__ float Bl[64][129];
    int t = threadIdx.x;
    int n = blockIdx.x >> 5;
    int k0 = (blockIdx.x & 31) << 7;
    const float* src = B + (size_t)n * RD * HD + k0;
#pragma unroll
    for (int rep = 0; rep < 8; ++rep) {
        int flat = (rep * 256 + t) * 4;
        int rr = flat >> 7, hh = flat & 127;
        float4v v = *(const float4v*)(src + (size_t)rr * HD + hh);
        Bl[rr][hh] = v[0]; Bl[rr][hh + 1] = v[1];
        Bl[rr][hh + 2] = v[2]; Bl[rr][hh + 3] = v[3];
    }
    __syncthreads();
    int i0 = (t >> 4) << 2;
    int j0 = (t & 15) << 2;
    float acc[4][4];
#pragma unroll
    for (int a = 0; a < 4; ++a)
#pragma unroll
        for (int b = 0; b < 4; ++b) acc[a][b] = 0.f;
    for (int h = 0; h < 128; ++h) {
        float bi[4], bj[4];
#pragma unroll
        for (int a = 0; a < 4; ++a) { bi[a] = Bl[i0 + a][h]; bj[a] = Bl[j0 + a][h]; }
#pragma unroll
        for (int a = 0; a < 4; ++a)
#pragma unroll
            for (int b = 0; b < 4; ++b) acc[a][b] += bi[a] * bj[b];
    }
    float* g = G + n * RD * RD;
#pragma unroll
    for (int a = 0; a < 4; ++a)
#pragma unroll
        for (int b = 0; b < 4; ++b)
            atomicAdd(&g[(i0 + a) * RD + j0 + b], acc[a][b]);
}

// GEMM1: inter[m][n*64+r] = x[m][:] . At[n*64+r][:]   (bf16 MFMA, KSPLIT=2)
__global__ __launch_bounds__(256) void k_gemm1(const float* __restrict__ x,
                                               const unsigned short* __restrict__ At,
                                               float* __restrict__ inter) {
    __shared__ unsigned short As[2][64 * 64];
    __shared__ unsigned short Bs[2][128 * 64];
    int t = threadIdx.x, lane = t & 63;
    int bid = blockIdx.x;
    int ks = bid & 1;
    int c0 = ((bid >> 1) & 3) * 128;
    int m0 = (bid >> 3) * 64;
    int kbase = ks * 2048;

    // A staging: each thread covers rows r0 = t>>3 and r1 = r0+32, segment sg = t&7
    int sa_r0 = t >> 3, sa_sg = t & 7;
    int sa_sw = sa_sg ^ (sa_r0 & 7);   // (r0+32)&7 == r0&7, same swizzle
    const float* xrow0 = x + (size_t)(m0 + sa_r0) * HD + sa_sg * 8;
    const float* xrow1 = x + (size_t)(m0 + sa_r0 + 32) * HD + sa_sg * 8;

    int wv = t >> 6;
    int wm = (wv >> 1) * 32;
    int wc = (wv & 1) * 64;

    f32x4 acc[2][4];
#pragma unroll
    for (int mf = 0; mf < 2; ++mf)
#pragma unroll
        for (int nf = 0; nf < 4; ++nf) acc[mf][nf] = (f32x4){0.f, 0.f, 0.f, 0.f};

    // prologue stage kt=0 -> buf 0
    {
#pragma unroll
        for (int q = 0; q < 4; ++q) {
            int flat = q * 256 + t;
            int c = flat >> 3, sg = flat & 7;
            int sw = sg ^ (c & 7);
            gload_lds16(At + (size_t)(c0 + c) * HD + kbase + sw * 8,
                        (void*)&Bs[0][(q * 256 + (t & ~63)) * 8]);
        }
        float4v a0 = *(const float4v*)(xrow0 + kbase);
        float4v a1 = *(const float4v*)(xrow0 + kbase + 4);
        float4v b0 = *(const float4v*)(xrow1 + kbase);
        float4v b1 = *(const float4v*)(xrow1 + kbase + 4);
        ushort8 sva, svb;
#pragma unroll
        for (int j = 0; j < 4; ++j) {
            sva[j] = f2bf(a0[j]); sva[j + 4] = f2bf(a1[j]);
            svb[j] = f2bf(b0[j]); svb[j + 4] = f2bf(b1[j]);
        }
        *(ushort8*)&As[0][sa_r0 * 64 + sa_sw * 8] = sva;
        *(ushort8*)&As[0][(sa_r0 + 32) * 64 + sa_sw * 8] = svb;
    }
    __syncthreads();

    float4v pa0, pa1, pb0, pb1;
    for (int kt = 0; kt < 32; ++kt) {
        int cur = kt & 1;
        int knext = kbase + (kt + 1) * 64;
        if (kt < 31) {
#pragma unroll
            for (int q = 0; q < 4; ++q) {
                int flat = q * 256 + t;
                int c = flat >> 3, sg = flat & 7;
                int sw = sg ^ (c & 7);
                gload_lds16(At + (size_t)(c0 + c) * HD + knext + sw * 8,
                            (void*)&Bs[cur ^ 1][(q * 256 + (t & ~63)) * 8]);
            }
            pa0 = *(const float4v*)(xrow0 + knext);
            pa1 = *(const float4v*)(xrow0 + knext + 4);
            pb0 = *(const float4v*)(xrow1 + knext);
            pb1 = *(const float4v*)(xrow1 + knext + 4);
        }
        const unsigned short* as = As[cur];
        const unsigned short* bs = Bs[cur];
#pragma unroll
        for (int kk = 0; kk < 2; ++kk) {
            bf16x8 af[2], bfr[4];
#pragma unroll
            for (int mf = 0; mf < 2; ++mf) {
                int row = wm + mf * 16 + (lane & 15);
                int seg = kk * 4 + (lane >> 4);
                af[mf] = *(const bf16x8*)&as[row * 64 + (seg ^ (row & 7)) * 8];
            }
#pragma unroll
            for (int nf = 0; nf < 4; ++nf) {
                int col = wc + nf * 16 + (lane & 15);
                int seg = kk * 4 + (lane >> 4);
                bfr[nf] = *(const bf16x8*)&bs[col * 64 + (seg ^ (col & 7)) * 8];
            }
#pragma unroll
            for (int mf = 0; mf < 2; ++mf)
#pragma unroll
                for (int nf = 0; nf < 4; ++nf)
                    acc[mf][nf] = __builtin_amdgcn_mfma_f32_16x16x32_bf16(
                        af[mf], bfr[nf], acc[mf][nf], 0, 0, 0);
        }
        if (kt < 31) {
            ushort8 sva, svb;
#pragma unroll
            for (int j = 0; j < 4; ++j) {
                sva[j] = f2bf(pa0[j]); sva[j + 4] = f2bf(pa1[j]);
                svb[j] = f2bf(pb0[j]); svb[j + 4] = f2bf(pb1[j]);
            }
            *(ushort8*)&As[cur ^ 1][sa_r0 * 64 + sa_sw * 8] = sva;
            *(ushort8*)&As[cur ^ 1][(sa_r0 + 32) * 64 + sa_sw * 8] = svb;
        }
        __syncthreads();
    }
#pragma unroll
    for (int mf = 0; mf < 2; ++mf)
#pragma unroll
        for (int nf = 0; nf < 4; ++nf)
#pragma unroll
            for (int i = 0; i < 4; ++i) {
                int row = m0 + wm + mf * 16 + (lane >> 4) * 4 + i;
                int col = c0 + wc + nf * 16 + (lane & 15);
                atomicAdd(&inter[(size_t)row * NGC + col], acc[mf][nf][i]);
            }
}

// s[n][m] = 2 / (sqrt(i^T G_n i) + 1e-8)
__global__ __launch_bounds__(256) void k_scale(const float* __restrict__ inter,
                                               const float* __restrict__ G,
                                               float* __restrict__ s) {
    int gw = blockIdx.x * 4 + (threadIdx.x >> 6);
    int lane = threadIdx.x & 63;
    int n = gw >> 12;
    int m = gw & 4095;
    float Iv = inter[(size_t)m * NGC + n * RD + lane];
    const float* g = G + (size_t)(n * RD + lane) * RD;
    float tsum = 0.f;
    for (int j = 0; j < 64; ++j) tsum += g[j] * __shfl(Iv, j);
    float p = Iv * tsum;
#pragma unroll
    for (int off = 32; off; off >>= 1) p += __shfl_xor(p, off);
    if (lane == 0) s[gw] = 2.0f / (sqrtf(fmaxf(p, 0.f)) + 1e-8f);
}

// GEMM2 fused: out[n][m][h] = x[m][h] + s[n][m] * (inter[m][n*64:] . Bt[n][h][:])
__global__ __launch_bounds__(256) void k_gemm2(const float* __restrict__ x,
                                               const float* __restrict__ inter,
                                               const unsigned short* __restrict__ Bt,
                                               const float* __restrict__ s,
                                               float* __restrict__ out) {
    __shared__ unsigned short As[64 * 64];
    __shared__ unsigned short Bs[256 * 64];
    int t = threadIdx.x, lane = t & 63, wv = t >> 6;
    int bid = blockIdx.x;
    int n = bid >> 10;
    int m0 = ((bid >> 4) & 63) * 64;
    int h0 = (bid & 15) * 256;

#pragma unroll
    for (int q = 0; q < 8; ++q) {
        int flat = q * 256 + t;
        int h = flat >> 3, sg = flat & 7;
        int sw = sg ^ (h & 7);
        gload_lds16(Bt + (size_t)(n * HD + h0 + h) * RD + sw * 8,
                    (void*)&Bs[(q * 256 + (t & ~63)) * 8]);
    }
    {
        // two rows per thread: m = t>>3 and +32
        int r0 = t >> 3, sg = t & 7;
        int sw = sg ^ (r0 & 7);
        const float* isrc0 = inter + (size_t)(m0 + r0) * NGC + n * RD + sg * 8;
        const float* isrc1 = inter + (size_t)(m0 + r0 + 32) * NGC + n * RD + sg * 8;
        float4v a0 = *(const float4v*)isrc0;
        float4v a1 = *(const float4v*)(isrc0 + 4);
        float4v b0 = *(const float4v*)isrc1;
        float4v b1 = *(const float4v*)(isrc1 + 4);
        ushort8 sva, svb;
#pragma unroll
        for (int j = 0; j < 4; ++j) {
            sva[j] = f2bf(a0[j]); sva[j + 4] = f2bf(a1[j]);
            svb[j] = f2bf(b0[j]); svb[j + 4] = f2bf(b1[j]);
        }
        *(ushort8*)&As[r0 * 64 + sw * 8] = sva;
        *(ushort8*)&As[(r0 + 32) * 64 + sw * 8] = svb;
    }
    __syncthreads();

    int wm = (wv >> 1) * 32;
    int wh = (wv & 1) * 128;
    f32x4 acc[2][8];
#pragma unroll
    for (int mf = 0; mf < 2; ++mf)
#pragma unroll
        for (int nf = 0; nf < 8; ++nf) acc[mf][nf] = (f32x4){0.f, 0.f, 0.f, 0.f};

#pragma unroll
    for (int kk = 0; kk < 2; ++kk) {
        int seg = kk * 4 + (lane >> 4);
        bf16x8 af[2];
#pragma unroll
        for (int mf = 0; mf < 2; ++mf) {
            int row = wm + mf * 16 + (lane & 15);
            af[mf] = *(const bf16x8*)&As[row * 64 + (seg ^ (row & 7)) * 8];
        }
#pragma unroll
        for (int nf = 0; nf < 8; ++nf) {
            int col = wh + nf * 16 + (lane & 15);
            bf16x8 bfr = *(const bf16x8*)&Bs[col * 64 + (seg ^ (col & 7)) * 8];
#pragma unroll
            for (int mf = 0; mf < 2; ++mf)
                acc[mf][nf] = __builtin_amdgcn_mfma_f32_16x16x32_bf16(
                    af[mf], bfr, acc[mf][nf], 0, 0, 0);
        }
    }

    size_t obase = (size_t)n * MD * HD;
#pragma unroll
    for (int mf = 0; mf < 2; ++mf)
#pragma unroll
        for (int i = 0; i < 4; ++i) {
            int m = m0 + wm + mf * 16 + (lane >> 4) * 4 + i;
            float sv = s[n * MD + m];
#pragma unroll
            for (int nf = 0; nf < 8; ++nf) {
                int h = h0 + wh + nf * 16 + (lane & 15);
                out[obase + (size_t)m * HD + h] = x[(size_t)m * HD + h] + sv * acc[mf][nf][i];
            }
        }
}

extern "C" void kernel_launch(void* const* d_in, const int* in_sizes, int n_in,
                              void* d_out, int out_size, void* d_ws, size_t ws_size,
                              hipStream_t stream) {
    const float* x = (const float*)d_in[0];
    const float* lA = (const float*)d_in[1];
    const float* lB = (const float*)d_in[2];
    float* out = (float*)d_out;
    char* ws = (char*)d_ws;
    unsigned short* At = (unsigned short*)(ws);                // 4 MB
    unsigned short* Bt = (unsigned short*)(ws + 4194304);      // 4 MB
    float* inter = (float*)(ws + 8388608);                     // 8 MB
    float* G = (float*)(ws + 16777216);                        // 128 KB
    float* s = (float*)(ws + 16908288);                        // 128 KB

    hipMemsetAsync(G, 0, NL * RD * RD * sizeof(float), stream);
    hipMemsetAsync(inter, 0, (size_t)MD * NGC * sizeof(float), stream);
    k_prep_A<<<512, 256, 0, stream>>>(lA, At);
    k_prep_B<<<512, 256, 0, stream>>>(lB, Bt);
    k_gram<<<256, 256, 0, stream>>>(lB, G);
    k_gemm1<<<512, 256, 0, stream>>>(x, At, inter);
    k_scale<<<8192, 256, 0, stream>>>(inter, G, s);
    k_gemm2<<<8192, 256, 0, stream>>>(x, inter, Bt, s, out);
}

// Round 3
// 322.869 us; speedup vs baseline: 1.0295x; 1.0295x over previous
//
#include <hip/hip_runtime.h>
#include <hip/hip_bf16.h>

#define NL 8
#define HD 4096
#define RD 64
#define MD 4096
#define NGC 512  // NL*RD

typedef __bf16 bf16x8 __attribute__((ext_vector_type(8)));
typedef float f32x4 __attribute__((ext_vector_type(4)));
typedef unsigned short ushort8 __attribute__((ext_vector_type(8)));
typedef float float4v __attribute__((ext_vector_type(4)));

__device__ __forceinline__ unsigned short f2bf(float f) {
    union { __hip_bfloat16 b; unsigned short u; } c;
    c.b = __float2bfloat16(f);
    return c.u;
}

__device__ __forceinline__ void gload_lds16(const void* g, void* l) {
    auto gp = (const __attribute__((address_space(1))) unsigned int*)(g);
    auto lp = (__attribute__((address_space(3))) unsigned int*)(l);
    __builtin_amdgcn_global_load_lds(gp, lp, 16, 0, 0);
}

// lora_A [NL][HD][RD] f32 -> At [NL*RD][HD] bf16  (At[n*64+r][h] = A[n][h][r])
__global__ __launch_bounds__(256) void k_prep_A(const float* __restrict__ A,
                                                unsigned short* __restrict__ At) {
    __shared__ unsigned short T[64][65];
    int t = threadIdx.x;
    int n = blockIdx.x >> 6;
    int h0 = (blockIdx.x & 63) << 6;
    const float* src = A + (size_t)n * HD * RD;
#pragma unroll
    for (int rep = 0; rep < 16; ++rep) {
        int flat = rep * 256 + t;
        int hh = flat >> 6, rr = flat & 63;
        T[hh][rr] = f2bf(src[(size_t)(h0 + hh) * RD + rr]);
    }
    __syncthreads();
#pragma unroll
    for (int rep = 0; rep < 16; ++rep) {
        int flat = rep * 256 + t;
        int rr = flat >> 6, hh = flat & 63;
        At[(size_t)(n * RD + rr) * HD + h0 + hh] = T[hh][rr];
    }
}

// lora_B [NL][RD][HD] f32 -> Bt [NL][HD][RD] bf16  (Bt[n][h][r] = B[n][r][h])
__global__ __launch_bounds__(256) void k_prep_B(const float* __restrict__ B,
                                                unsigned short* __restrict__ Bt) {
    __shared__ unsigned short T[64][65];
    int t = threadIdx.x;
    int n = blockIdx.x >> 6;
    int h0 = (blockIdx.x & 63) << 6;
    const float* src = B + (size_t)n * RD * HD;
#pragma unroll
    for (int rep = 0; rep < 16; ++rep) {
        int flat = rep * 256 + t;
        int rr = flat >> 6, hh = flat & 63;
        T[rr][hh] = f2bf(src[(size_t)rr * HD + h0 + hh]);
    }
    __syncthreads();
    unsigned short* dst = Bt + (size_t)n * HD * RD;
#pragma unroll
    for (int rep = 0; rep < 16; ++rep) {
        int flat = rep * 256 + t;
        int hh = flat >> 6, rr = flat & 63;
        dst[(size_t)(h0 + hh) * RD + rr] = T[rr][hh];
    }
}

// Gram partials: Gp[n][c][64][64] = B_n[:, c*128:(c+1)*128] @ (same)^T  (plain stores)
__global__ __launch_bounds__(256) void k_gram(const float* __restrict__ B,
                                              float* __restrict__ Gp) {
    __shared__ float Bl[64][129];
    int t = threadIdx.x;
    int n = blockIdx.x >> 5;
    int c = blockIdx.x & 31;
    int k0 = c << 7;
    const float* src = B + (size_t)n * RD * HD + k0;
#pragma unroll
    for (int rep = 0; rep < 8; ++rep) {
        int flat = (rep * 256 + t) * 4;
        int rr = flat >> 7, hh = flat & 127;
        float4v v = *(const float4v*)(src + (size_t)rr * HD + hh);
        Bl[rr][hh] = v[0]; Bl[rr][hh + 1] = v[1];
        Bl[rr][hh + 2] = v[2]; Bl[rr][hh + 3] = v[3];
    }
    __syncthreads();
    int i0 = (t >> 4) << 2;
    int j0 = (t & 15) << 2;
    float acc[4][4];
#pragma unroll
    for (int a = 0; a < 4; ++a)
#pragma unroll
        for (int b = 0; b < 4; ++b) acc[a][b] = 0.f;
    for (int h = 0; h < 128; ++h) {
        float bi[4], bj[4];
#pragma unroll
        for (int a = 0; a < 4; ++a) { bi[a] = Bl[i0 + a][h]; bj[a] = Bl[j0 + a][h]; }
#pragma unroll
        for (int a = 0; a < 4; ++a)
#pragma unroll
            for (int b = 0; b < 4; ++b) acc[a][b] += bi[a] * bj[b];
    }
    float* g = Gp + (size_t)(n * 32 + c) * RD * RD;
#pragma unroll
    for (int a = 0; a < 4; ++a)
#pragma unroll
        for (int b = 0; b < 4; ++b)
            g[(i0 + a) * RD + j0 + b] = acc[a][b];
}

// G[n][i][j] = sum_c Gp[n][c][i][j]
__global__ __launch_bounds__(256) void k_gram_reduce(const float* __restrict__ Gp,
                                                     float* __restrict__ G) {
    int idx = blockIdx.x * 256 + threadIdx.x;   // 0..32767
    int n = idx >> 12;
    int rem = idx & 4095;
    const float* src = Gp + (size_t)n * 32 * 4096 + rem;
    float sum = 0.f;
#pragma unroll
    for (int c = 0; c < 32; ++c) sum += src[(size_t)c * 4096];
    G[idx] = sum;
}

// GEMM1: inter_p[ks][m][n*64+r] = x[m][k in split ks] . At[n*64+r][k]  (plain stores)
__global__ __launch_bounds__(256) void k_gemm1(const float* __restrict__ x,
                                               const unsigned short* __restrict__ At,
                                               float* __restrict__ inter_p) {
    __shared__ unsigned short As[2][64 * 64];
    __shared__ unsigned short Bs[2][128 * 64];
    int t = threadIdx.x, lane = t & 63;
    int bid = blockIdx.x;
    int ks = bid & 1;
    int c0 = ((bid >> 1) & 3) * 128;
    int m0 = (bid >> 3) * 64;
    int kbase = ks * 2048;

    int sa_r0 = t >> 3, sa_sg = t & 7;
    int sa_sw = sa_sg ^ (sa_r0 & 7);
    const float* xrow0 = x + (size_t)(m0 + sa_r0) * HD + sa_sg * 8;
    const float* xrow1 = x + (size_t)(m0 + sa_r0 + 32) * HD + sa_sg * 8;

    int wv = t >> 6;
    int wm = (wv >> 1) * 32;
    int wc = (wv & 1) * 64;

    f32x4 acc[2][4];
#pragma unroll
    for (int mf = 0; mf < 2; ++mf)
#pragma unroll
        for (int nf = 0; nf < 4; ++nf) acc[mf][nf] = (f32x4){0.f, 0.f, 0.f, 0.f};

    {
#pragma unroll
        for (int q = 0; q < 4; ++q) {
            int flat = q * 256 + t;
            int cc = flat >> 3, sg = flat & 7;
            int sw = sg ^ (cc & 7);
            gload_lds16(At + (size_t)(c0 + cc) * HD + kbase + sw * 8,
                        (void*)&Bs[0][(q * 256 + (t & ~63)) * 8]);
        }
        float4v a0 = *(const float4v*)(xrow0 + kbase);
        float4v a1 = *(const float4v*)(xrow0 + kbase + 4);
        float4v b0 = *(const float4v*)(xrow1 + kbase);
        float4v b1 = *(const float4v*)(xrow1 + kbase + 4);
        ushort8 sva, svb;
#pragma unroll
        for (int j = 0; j < 4; ++j) {
            sva[j] = f2bf(a0[j]); sva[j + 4] = f2bf(a1[j]);
            svb[j] = f2bf(b0[j]); svb[j + 4] = f2bf(b1[j]);
        }
        *(ushort8*)&As[0][sa_r0 * 64 + sa_sw * 8] = sva;
        *(ushort8*)&As[0][(sa_r0 + 32) * 64 + sa_sw * 8] = svb;
    }
    __syncthreads();

    float4v pa0, pa1, pb0, pb1;
    for (int kt = 0; kt < 32; ++kt) {
        int cur = kt & 1;
        int knext = kbase + (kt + 1) * 64;
        if (kt < 31) {
#pragma unroll
            for (int q = 0; q < 4; ++q) {
                int flat = q * 256 + t;
                int cc = flat >> 3, sg = flat & 7;
                int sw = sg ^ (cc & 7);
                gload_lds16(At + (size_t)(c0 + cc) * HD + knext + sw * 8,
                            (void*)&Bs[cur ^ 1][(q * 256 + (t & ~63)) * 8]);
            }
            pa0 = *(const float4v*)(xrow0 + knext);
            pa1 = *(const float4v*)(xrow0 + knext + 4);
            pb0 = *(const float4v*)(xrow1 + knext);
            pb1 = *(const float4v*)(xrow1 + knext + 4);
        }
        const unsigned short* as = As[cur];
        const unsigned short* bs = Bs[cur];
#pragma unroll
        for (int kk = 0; kk < 2; ++kk) {
            bf16x8 af[2], bfr[4];
#pragma unroll
            for (int mf = 0; mf < 2; ++mf) {
                int row = wm + mf * 16 + (lane & 15);
                int seg = kk * 4 + (lane >> 4);
                af[mf] = *(const bf16x8*)&as[row * 64 + (seg ^ (row & 7)) * 8];
            }
#pragma unroll
            for (int nf = 0; nf < 4; ++nf) {
                int col = wc + nf * 16 + (lane & 15);
                int seg = kk * 4 + (lane >> 4);
                bfr[nf] = *(const bf16x8*)&bs[col * 64 + (seg ^ (col & 7)) * 8];
            }
#pragma unroll
            for (int mf = 0; mf < 2; ++mf)
#pragma unroll
                for (int nf = 0; nf < 4; ++nf)
                    acc[mf][nf] = __builtin_amdgcn_mfma_f32_16x16x32_bf16(
                        af[mf], bfr[nf], acc[mf][nf], 0, 0, 0);
        }
        if (kt < 31) {
            ushort8 sva, svb;
#pragma unroll
            for (int j = 0; j < 4; ++j) {
                sva[j] = f2bf(pa0[j]); sva[j + 4] = f2bf(pa1[j]);
                svb[j] = f2bf(pb0[j]); svb[j + 4] = f2bf(pb1[j]);
            }
            *(ushort8*)&As[cur ^ 1][sa_r0 * 64 + sa_sw * 8] = sva;
            *(ushort8*)&As[cur ^ 1][(sa_r0 + 32) * 64 + sa_sw * 8] = svb;
        }
        __syncthreads();
    }
    float* dst = inter_p + (size_t)ks * MD * NGC;
#pragma unroll
    for (int mf = 0; mf < 2; ++mf)
#pragma unroll
        for (int nf = 0; nf < 4; ++nf)
#pragma unroll
            for (int i = 0; i < 4; ++i) {
                int row = m0 + wm + mf * 16 + (lane >> 4) * 4 + i;
                int col = c0 + wc + nf * 16 + (lane & 15);
                dst[(size_t)row * NGC + col] = acc[mf][nf][i];
            }
}

// s[n][m] = 2 / (sqrt(i^T G_n i) + 1e-8); also emit summed bf16 intermediate
__global__ __launch_bounds__(256) void k_scale(const float* __restrict__ inter_p,
                                               const float* __restrict__ G,
                                               float* __restrict__ s,
                                               unsigned short* __restrict__ interbf) {
    int gw = blockIdx.x * 4 + (threadIdx.x >> 6);
    int lane = threadIdx.x & 63;
    int n = gw >> 12;
    int m = gw & 4095;
    size_t off = (size_t)m * NGC + n * RD + lane;
    float Iv = inter_p[off] + inter_p[(size_t)MD * NGC + off];
    interbf[off] = f2bf(Iv);
    const float* g = G + (size_t)(n * RD + lane) * RD;
    float tsum = 0.f;
    for (int j = 0; j < 64; ++j) tsum += g[j] * __shfl(Iv, j);
    float p = Iv * tsum;
#pragma unroll
    for (int off2 = 32; off2; off2 >>= 1) p += __shfl_xor(p, off2);
    if (lane == 0) s[gw] = 2.0f / (sqrtf(fmaxf(p, 0.f)) + 1e-8f);
}

// GEMM2 fused: out[n][m][h] = x[m][h] + s[n][m] * (interbf[m][n*64:] . Bt[n][h][:])
__global__ __launch_bounds__(256) void k_gemm2(const float* __restrict__ x,
                                               const unsigned short* __restrict__ interbf,
                                               const unsigned short* __restrict__ Bt,
                                               const float* __restrict__ s,
                                               float* __restrict__ out) {
    __shared__ unsigned short As[64 * 64];
    __shared__ unsigned short Bs[256 * 64];
    int t = threadIdx.x, lane = t & 63, wv = t >> 6;
    int bid0 = blockIdx.x;
    int bid = (bid0 & 7) * 1024 + (bid0 >> 3);   // XCD swizzle: each XCD owns one n
    int n = bid >> 10;
    int m0 = ((bid >> 4) & 63) * 64;
    int h0 = (bid & 15) * 256;

#pragma unroll
    for (int q = 0; q < 8; ++q) {
        int flat = q * 256 + t;
        int h = flat >> 3, sg = flat & 7;
        int sw = sg ^ (h & 7);
        gload_lds16(Bt + (size_t)(n * HD + h0 + h) * RD + sw * 8,
                    (void*)&Bs[(q * 256 + (t & ~63)) * 8]);
    }
#pragma unroll
    for (int q = 0; q < 2; ++q) {
        int flat = q * 256 + t;
        int m = flat >> 3, sg = flat & 7;
        int sw = sg ^ (m & 7);
        gload_lds16(interbf + (size_t)(m0 + m) * NGC + n * RD + sw * 8,
                    (void*)&As[(q * 256 + (t & ~63)) * 8]);
    }
    __syncthreads();

    int wm = (wv >> 1) * 32;
    int wh = (wv & 1) * 128;
    f32x4 acc[2][8];
#pragma unroll
    for (int mf = 0; mf < 2; ++mf)
#pragma unroll
        for (int nf = 0; nf < 8; ++nf) acc[mf][nf] = (f32x4){0.f, 0.f, 0.f, 0.f};

#pragma unroll
    for (int kk = 0; kk < 2; ++kk) {
        int seg = kk * 4 + (lane >> 4);
        bf16x8 af[2];
#pragma unroll
        for (int mf = 0; mf < 2; ++mf) {
            int row = wm + mf * 16 + (lane & 15);
            af[mf] = *(const bf16x8*)&As[row * 64 + (seg ^ (row & 7)) * 8];
        }
#pragma unroll
        for (int nf = 0; nf < 8; ++nf) {
            int col = wh + nf * 16 + (lane & 15);
            bf16x8 bfr = *(const bf16x8*)&Bs[col * 64 + (seg ^ (col & 7)) * 8];
#pragma unroll
            for (int mf = 0; mf < 2; ++mf)
                acc[mf][nf] = __builtin_amdgcn_mfma_f32_16x16x32_bf16(
                    af[mf], bfr, acc[mf][nf], 0, 0, 0);
        }
    }

    size_t obase = (size_t)n * MD * HD;
#pragma unroll
    for (int mf = 0; mf < 2; ++mf)
#pragma unroll
        for (int i = 0; i < 4; ++i) {
            int m = m0 + wm + mf * 16 + (lane >> 4) * 4 + i;
            float sv = s[n * MD + m];
#pragma unroll
            for (int nf = 0; nf < 8; ++nf) {
                int h = h0 + wh + nf * 16 + (lane & 15);
                out[obase + (size_t)m * HD + h] = x[(size_t)m * HD + h] + sv * acc[mf][nf][i];
            }
        }
}

extern "C" void kernel_launch(void* const* d_in, const int* in_sizes, int n_in,
                              void* d_out, int out_size, void* d_ws, size_t ws_size,
                              hipStream_t stream) {
    const float* x = (const float*)d_in[0];
    const float* lA = (const float*)d_in[1];
    const float* lB = (const float*)d_in[2];
    float* out = (float*)d_out;
    char* ws = (char*)d_ws;
    unsigned short* At      = (unsigned short*)(ws);              //  4 MB
    unsigned short* Bt      = (unsigned short*)(ws + 4194304);    //  4 MB
    float*          inter_p = (float*)(ws + 8388608);             // 16 MB ([2][M][NGC])
    float*          Gp      = (float*)(ws + 25165824);            //  4 MB
    float*          G       = (float*)(ws + 29360128);            // 128 KB
    float*          s       = (float*)(ws + 29491200);            // 128 KB
    unsigned short* interbf = (unsigned short*)(ws + 29622272);   //  4 MB

    k_prep_A<<<512, 256, 0, stream>>>(lA, At);
    k_prep_B<<<512, 256, 0, stream>>>(lB, Bt);
    k_gram<<<256, 256, 0, stream>>>(lB, Gp);
    k_gram_reduce<<<128, 256, 0, stream>>>(Gp, G);
    k_gemm1<<<512, 256, 0, stream>>>(x, At, inter_p);
    k_scale<<<8192, 256, 0, stream>>>(inter_p, G, s, interbf);
    k_gemm2<<<8192, 256, 0, stream>>>(x, interbf, Bt, s, out);
}

// Round 4
// 267.085 us; speedup vs baseline: 1.2445x; 1.2089x over previous
//
#include <hip/hip_runtime.h>
#include <hip/hip_bf16.h>

#define NL 8
#define HD 4096
#define RD 64
#define MD 4096
#define NGC 512  // NL*RD

typedef __bf16 bf16x8 __attribute__((ext_vector_type(8)));
typedef float f32x4 __attribute__((ext_vector_type(4)));
typedef unsigned short ushort8 __attribute__((ext_vector_type(8)));
typedef float float4v __attribute__((ext_vector_type(4)));

__device__ __forceinline__ unsigned short f2bf(float f) {
    union { __hip_bfloat16 b; unsigned short u; } c;
    c.b = __float2bfloat16(f);
    return c.u;
}

__device__ __forceinline__ void gload_lds16(const void* g, void* l) {
    auto gp = (const __attribute__((address_space(1))) unsigned int*)(g);
    auto lp = (__attribute__((address_space(3))) unsigned int*)(l);
    __builtin_amdgcn_global_load_lds(gp, lp, 16, 0, 0);
}

// lora_A [NL][HD][RD] f32 -> At [NL*RD][HD] bf16  (At[n*64+r][h] = A[n][h][r])
__global__ __launch_bounds__(256) void k_prep_A(const float* __restrict__ A,
                                                unsigned short* __restrict__ At) {
    __shared__ unsigned short T[64][65];
    int t = threadIdx.x;
    int n = blockIdx.x >> 6;
    int h0 = (blockIdx.x & 63) << 6;
    const float* src = A + (size_t)n * HD * RD;
#pragma unroll
    for (int rep = 0; rep < 16; ++rep) {
        int flat = rep * 256 + t;
        int hh = flat >> 6, rr = flat & 63;
        T[hh][rr] = f2bf(src[(size_t)(h0 + hh) * RD + rr]);
    }
    __syncthreads();
#pragma unroll
    for (int rep = 0; rep < 16; ++rep) {
        int flat = rep * 256 + t;
        int rr = flat >> 6, hh = flat & 63;
        At[(size_t)(n * RD + rr) * HD + h0 + hh] = T[hh][rr];
    }
}

// lora_B [NL][RD][HD] f32 -> Bt [NL][HD][RD] bf16  (Bt[n][h][r] = B[n][r][h])
__global__ __launch_bounds__(256) void k_prep_B(const float* __restrict__ B,
                                                unsigned short* __restrict__ Bt) {
    __shared__ unsigned short T[64][65];
    int t = threadIdx.x;
    int n = blockIdx.x >> 6;
    int h0 = (blockIdx.x & 63) << 6;
    const float* src = B + (size_t)n * RD * HD;
#pragma unroll
    for (int rep = 0; rep < 16; ++rep) {
        int flat = rep * 256 + t;
        int rr = flat >> 6, hh = flat & 63;
        T[rr][hh] = f2bf(src[(size_t)rr * HD + h0 + hh]);
    }
    __syncthreads();
    unsigned short* dst = Bt + (size_t)n * HD * RD;
#pragma unroll
    for (int rep = 0; rep < 16; ++rep) {
        int flat = rep * 256 + t;
        int hh = flat >> 6, rr = flat & 63;
        dst[(size_t)(h0 + hh) * RD + rr] = T[rr][hh];
    }
}

// Gram partials: Gp[n][c][64][64] = B_n[:, c*128:(c+1)*128] @ (same)^T  (plain stores)
__global__ __launch_bounds__(256) void k_gram(const float* __restrict__ B,
                                              float* __restrict__ Gp) {
    __shared__ float Bl[64][129];
    int t = threadIdx.x;
    int n = blockIdx.x >> 5;
    int c = blockIdx.x & 31;
    int k0 = c << 7;
    const float* src = B + (size_t)n * RD * HD + k0;
#pragma unroll
    for (int rep = 0; rep < 8; ++rep) {
        int flat = (rep * 256 + t) * 4;
        int rr = flat >> 7, hh = flat & 127;
        float4v v = *(const float4v*)(src + (size_t)rr * HD + hh);
        Bl[rr][hh] = v[0]; Bl[rr][hh + 1] = v[1];
        Bl[rr][hh + 2] = v[2]; Bl[rr][hh + 3] = v[3];
    }
    __syncthreads();
    int i0 = (t >> 4) << 2;
    int j0 = (t & 15) << 2;
    float acc[4][4];
#pragma unroll
    for (int a = 0; a < 4; ++a)
#pragma unroll
        for (int b = 0; b < 4; ++b) acc[a][b] = 0.f;
    for (int h = 0; h < 128; ++h) {
        float bi[4], bj[4];
#pragma unroll
        for (int a = 0; a < 4; ++a) { bi[a] = Bl[i0 + a][h]; bj[a] = Bl[j0 + a][h]; }
#pragma unroll
        for (int a = 0; a < 4; ++a)
#pragma unroll
            for (int b = 0; b < 4; ++b) acc[a][b] += bi[a] * bj[b];
    }
    float* g = Gp + (size_t)(n * 32 + c) * RD * RD;
#pragma unroll
    for (int a = 0; a < 4; ++a)
#pragma unroll
        for (int b = 0; b < 4; ++b)
            g[(i0 + a) * RD + j0 + b] = acc[a][b];
}

// G[n][i][j] = sum_c Gp[n][c][i][j]
__global__ __launch_bounds__(256) void k_gram_reduce(const float* __restrict__ Gp,
                                                     float* __restrict__ G) {
    int idx = blockIdx.x * 256 + threadIdx.x;   // 0..32767
    int n = idx >> 12;
    int rem = idx & 4095;
    const float* src = Gp + (size_t)n * 32 * 4096 + rem;
    float sum = 0.f;
#pragma unroll
    for (int c = 0; c < 32; ++c) sum += src[(size_t)c * 4096];
    G[idx] = sum;
}

// GEMM1: inter_p[ks][m][n*64+r] = x[m][k in split ks] . At[n*64+r][k]  (plain stores)
__global__ __launch_bounds__(256) void k_gemm1(const float* __restrict__ x,
                                               const unsigned short* __restrict__ At,
                                               float* __restrict__ inter_p) {
    __shared__ unsigned short As[2][64 * 64];
    __shared__ unsigned short Bs[2][128 * 64];
    int t = threadIdx.x, lane = t & 63;
    int bid = blockIdx.x;
    int ks = bid & 1;
    int c0 = ((bid >> 1) & 3) * 128;
    int m0 = (bid >> 3) * 64;
    int kbase = ks * 2048;

    int sa_r0 = t >> 3, sa_sg = t & 7;
    int sa_sw = sa_sg ^ (sa_r0 & 7);
    const float* xrow0 = x + (size_t)(m0 + sa_r0) * HD + sa_sg * 8;
    const float* xrow1 = x + (size_t)(m0 + sa_r0 + 32) * HD + sa_sg * 8;

    int wv = t >> 6;
    int wm = (wv >> 1) * 32;
    int wc = (wv & 1) * 64;

    f32x4 acc[2][4];
#pragma unroll
    for (int mf = 0; mf < 2; ++mf)
#pragma unroll
        for (int nf = 0; nf < 4; ++nf) acc[mf][nf] = (f32x4){0.f, 0.f, 0.f, 0.f};

    {
#pragma unroll
        for (int q = 0; q < 4; ++q) {
            int flat = q * 256 + t;
            int cc = flat >> 3, sg = flat & 7;
            int sw = sg ^ (cc & 7);
            gload_lds16(At + (size_t)(c0 + cc) * HD + kbase + sw * 8,
                        (void*)&Bs[0][(q * 256 + (t & ~63)) * 8]);
        }
        float4v a0 = *(const float4v*)(xrow0 + kbase);
        float4v a1 = *(const float4v*)(xrow0 + kbase + 4);
        float4v b0 = *(const float4v*)(xrow1 + kbase);
        float4v b1 = *(const float4v*)(xrow1 + kbase + 4);
        ushort8 sva, svb;
#pragma unroll
        for (int j = 0; j < 4; ++j) {
            sva[j] = f2bf(a0[j]); sva[j + 4] = f2bf(a1[j]);
            svb[j] = f2bf(b0[j]); svb[j + 4] = f2bf(b1[j]);
        }
        *(ushort8*)&As[0][sa_r0 * 64 + sa_sw * 8] = sva;
        *(ushort8*)&As[0][(sa_r0 + 32) * 64 + sa_sw * 8] = svb;
    }
    __syncthreads();

    float4v pa0, pa1, pb0, pb1;
    for (int kt = 0; kt < 32; ++kt) {
        int cur = kt & 1;
        int knext = kbase + (kt + 1) * 64;
        if (kt < 31) {
#pragma unroll
            for (int q = 0; q < 4; ++q) {
                int flat = q * 256 + t;
                int cc = flat >> 3, sg = flat & 7;
                int sw = sg ^ (cc & 7);
                gload_lds16(At + (size_t)(c0 + cc) * HD + knext + sw * 8,
                            (void*)&Bs[cur ^ 1][(q * 256 + (t & ~63)) * 8]);
            }
            pa0 = *(const float4v*)(xrow0 + knext);
            pa1 = *(const float4v*)(xrow0 + knext + 4);
            pb0 = *(const float4v*)(xrow1 + knext);
            pb1 = *(const float4v*)(xrow1 + knext + 4);
        }
        const unsigned short* as = As[cur];
        const unsigned short* bs = Bs[cur];
#pragma unroll
        for (int kk = 0; kk < 2; ++kk) {
            bf16x8 af[2], bfr[4];
#pragma unroll
            for (int mf = 0; mf < 2; ++mf) {
                int row = wm + mf * 16 + (lane & 15);
                int seg = kk * 4 + (lane >> 4);
                af[mf] = *(const bf16x8*)&as[row * 64 + (seg ^ (row & 7)) * 8];
            }
#pragma unroll
            for (int nf = 0; nf < 4; ++nf) {
                int col = wc + nf * 16 + (lane & 15);
                int seg = kk * 4 + (lane >> 4);
                bfr[nf] = *(const bf16x8*)&bs[col * 64 + (seg ^ (col & 7)) * 8];
            }
#pragma unroll
            for (int mf = 0; mf < 2; ++mf)
#pragma unroll
                for (int nf = 0; nf < 4; ++nf)
                    acc[mf][nf] = __builtin_amdgcn_mfma_f32_16x16x32_bf16(
                        af[mf], bfr[nf], acc[mf][nf], 0, 0, 0);
        }
        if (kt < 31) {
            ushort8 sva, svb;
#pragma unroll
            for (int j = 0; j < 4; ++j) {
                sva[j] = f2bf(pa0[j]); sva[j + 4] = f2bf(pa1[j]);
                svb[j] = f2bf(pb0[j]); svb[j + 4] = f2bf(pb1[j]);
            }
            *(ushort8*)&As[cur ^ 1][sa_r0 * 64 + sa_sw * 8] = sva;
            *(ushort8*)&As[cur ^ 1][(sa_r0 + 32) * 64 + sa_sw * 8] = svb;
        }
        __syncthreads();
    }
    float* dst = inter_p + (size_t)ks * MD * NGC;
#pragma unroll
    for (int mf = 0; mf < 2; ++mf)
#pragma unroll
        for (int nf = 0; nf < 4; ++nf)
#pragma unroll
            for (int i = 0; i < 4; ++i) {
                int row = m0 + wm + mf * 16 + (lane >> 4) * 4 + i;
                int col = c0 + wc + nf * 16 + (lane & 15);
                dst[(size_t)row * NGC + col] = acc[mf][nf][i];
            }
}

// s[n][m] = 2 / (sqrt(i^T G_n i) + 1e-8); also emit summed bf16 intermediate
__global__ __launch_bounds__(256) void k_scale(const float* __restrict__ inter_p,
                                               const float* __restrict__ G,
                                               float* __restrict__ s,
                                               unsigned short* __restrict__ interbf) {
    int gw = blockIdx.x * 4 + (threadIdx.x >> 6);
    int lane = threadIdx.x & 63;
    int n = gw >> 12;
    int m = gw & 4095;
    size_t off = (size_t)m * NGC + n * RD + lane;
    float Iv = inter_p[off] + inter_p[(size_t)MD * NGC + off];
    interbf[off] = f2bf(Iv);
    const float* g = G + (size_t)(n * RD + lane) * RD;
    float tsum = 0.f;
    for (int j = 0; j < 64; ++j) tsum += g[j] * __shfl(Iv, j);
    float p = Iv * tsum;
#pragma unroll
    for (int off2 = 32; off2; off2 >>= 1) p += __shfl_xor(p, off2);
    if (lane == 0) s[gw] = 2.0f / (sqrtf(fmaxf(p, 0.f)) + 1e-8f);
}

// GEMM2 fused, n-loop inside block: each block owns (m0:64, h0:256) and loops n=0..7.
// x tile fetched once (L1/L2-resident for all 8 n); Bt slab L2-resident per XCD.
__global__ __launch_bounds__(256) void k_gemm2(const float* __restrict__ x,
                                               const unsigned short* __restrict__ interbf,
                                               const unsigned short* __restrict__ Bt,
                                               const float* __restrict__ s,
                                               float* __restrict__ out) {
    __shared__ unsigned short As[2][64 * 64];
    __shared__ unsigned short Bs[2][256 * 64];
    int t = threadIdx.x, lane = t & 63, wv = t >> 6;
    int b = blockIdx.x;
    int xcd = b & 7;
    int idx = b >> 3;                       // 0..127
    int h0 = (xcd * 2 + (idx >> 6)) * 256;  // 2 h-slabs per XCD
    int m0 = (idx & 63) * 64;

    int wm = (wv >> 1) * 32;
    int wh = (wv & 1) * 128;

    // prologue: stage n=0 into buf 0
#pragma unroll
    for (int q = 0; q < 8; ++q) {
        int flat = q * 256 + t;
        int h = flat >> 3, sg = flat & 7;
        int sw = sg ^ (h & 7);
        gload_lds16(Bt + (size_t)(0 * HD + h0 + h) * RD + sw * 8,
                    (void*)&Bs[0][(q * 256 + (t & ~63)) * 8]);
    }
#pragma unroll
    for (int q = 0; q < 2; ++q) {
        int flat = q * 256 + t;
        int m = flat >> 3, sg = flat & 7;
        int sw = sg ^ (m & 7);
        gload_lds16(interbf + (size_t)(m0 + m) * NGC + 0 * RD + sw * 8,
                    (void*)&As[0][(q * 256 + (t & ~63)) * 8]);
    }
    __syncthreads();

    for (int n = 0; n < NL; ++n) {
        int cur = n & 1;
        if (n < NL - 1) {
            // prefetch n+1 into the other buffer; drained by end-of-iter barrier
#pragma unroll
            for (int q = 0; q < 8; ++q) {
                int flat = q * 256 + t;
                int h = flat >> 3, sg = flat & 7;
                int sw = sg ^ (h & 7);
                gload_lds16(Bt + (size_t)((n + 1) * HD + h0 + h) * RD + sw * 8,
                            (void*)&Bs[cur ^ 1][(q * 256 + (t & ~63)) * 8]);
            }
#pragma unroll
            for (int q = 0; q < 2; ++q) {
                int flat = q * 256 + t;
                int m = flat >> 3, sg = flat & 7;
                int sw = sg ^ (m & 7);
                gload_lds16(interbf + (size_t)(m0 + m) * NGC + (n + 1) * RD + sw * 8,
                            (void*)&As[cur ^ 1][(q * 256 + (t & ~63)) * 8]);
            }
        }

        f32x4 acc[2][8];
#pragma unroll
        for (int mf = 0; mf < 2; ++mf)
#pragma unroll
            for (int nf = 0; nf < 8; ++nf) acc[mf][nf] = (f32x4){0.f, 0.f, 0.f, 0.f};

        const unsigned short* as = As[cur];
        const unsigned short* bs = Bs[cur];
#pragma unroll
        for (int kk = 0; kk < 2; ++kk) {
            int seg = kk * 4 + (lane >> 4);
            bf16x8 af[2];
#pragma unroll
            for (int mf = 0; mf < 2; ++mf) {
                int row = wm + mf * 16 + (lane & 15);
                af[mf] = *(const bf16x8*)&as[row * 64 + (seg ^ (row & 7)) * 8];
            }
#pragma unroll
            for (int nf = 0; nf < 8; ++nf) {
                int col = wh + nf * 16 + (lane & 15);
                bf16x8 bfr = *(const bf16x8*)&bs[col * 64 + (seg ^ (col & 7)) * 8];
#pragma unroll
                for (int mf = 0; mf < 2; ++mf)
                    acc[mf][nf] = __builtin_amdgcn_mfma_f32_16x16x32_bf16(
                        af[mf], bfr, acc[mf][nf], 0, 0, 0);
            }
        }

        // fused epilogue: out[n][m][h] = x[m][h] + s[n][m] * acc
        size_t obase = (size_t)n * MD * HD;
#pragma unroll
        for (int mf = 0; mf < 2; ++mf)
#pragma unroll
            for (int i = 0; i < 4; ++i) {
                int m = m0 + wm + mf * 16 + (lane >> 4) * 4 + i;
                float sv = s[n * MD + m];
#pragma unroll
                for (int nf = 0; nf < 8; ++nf) {
                    int h = h0 + wh + nf * 16 + (lane & 15);
                    out[obase + (size_t)m * HD + h] = x[(size_t)m * HD + h] + sv * acc[mf][nf][i];
                }
            }
        __syncthreads();   // drains prefetch vmcnt + guards buffer overwrite
    }
}

extern "C" void kernel_launch(void* const* d_in, const int* in_sizes, int n_in,
                              void* d_out, int out_size, void* d_ws, size_t ws_size,
                              hipStream_t stream) {
    const float* x = (const float*)d_in[0];
    const float* lA = (const float*)d_in[1];
    const float* lB = (const float*)d_in[2];
    float* out = (float*)d_out;
    char* ws = (char*)d_ws;
    unsigned short* At      = (unsigned short*)(ws);              //  4 MB
    unsigned short* Bt      = (unsigned short*)(ws + 4194304);    //  4 MB
    float*          inter_p = (float*)(ws + 8388608);             // 16 MB ([2][M][NGC])
    float*          Gp      = (float*)(ws + 25165824);            //  4 MB
    float*          G       = (float*)(ws + 29360128);            // 128 KB
    float*          s       = (float*)(ws + 29491200);            // 128 KB
    unsigned short* interbf = (unsigned short*)(ws + 29622272);   //  4 MB

    k_prep_A<<<512, 256, 0, stream>>>(lA, At);
    k_prep_B<<<512, 256, 0, stream>>>(lB, Bt);
    k_gram<<<256, 256, 0, stream>>>(lB, Gp);
    k_gram_reduce<<<128, 256, 0, stream>>>(Gp, G);
    k_gemm1<<<512, 256, 0, stream>>>(x, At, inter_p);
    k_scale<<<8192, 256, 0, stream>>>(inter_p, G, s, interbf);
    k_gemm2<<<1024, 256, 0, stream>>>(x, interbf, Bt, s, out);
}